// Round 14
// baseline (141.907 us; speedup 1.0000x reference)
//
#include <hip/hip_runtime.h>
#include <cstdint>
#include <cstddef>

#define B_ 4
#define L_ 2048
#define DMODEL 512
#define DINNER 1024
#define DSTATE 128
#define NH 16
#define HD 64
#define CONVDIM 1280          // DINNER + 2*DSTATE
#define NPROJ 2320            // 2*DINNER + 2*DSTATE + NH
#define NPAD 2432             // 19 * 128
#define ML (B_*L_)            // 8192 rows
#define Q_ 64                 // chunk length
#define NCH 32                // chunks per sequence

typedef __bf16 bf16x8 __attribute__((ext_vector_type(8)));
typedef float f32x4 __attribute__((ext_vector_type(4)));
typedef float f32x16 __attribute__((ext_vector_type(16)));

__device__ __forceinline__ float bf2f(ushort u) {
  union { unsigned int i; float f; } v; v.i = ((unsigned int)u) << 16; return v.f;
}
__device__ __forceinline__ ushort f2bf(float f) {
  union { float f; unsigned int i; } v; v.f = f;
  unsigned int u = v.i;
  unsigned int r = (u + 0x7fffu + ((u >> 16) & 1u)) >> 16;
  return (ushort)r;
}
__device__ __forceinline__ float siluf(float x) { return x / (1.f + __expf(-x)); }

// async global->LDS, 16B per lane; LDS dest is wave-uniform base + lane*16
__device__ __forceinline__ void gl_lds16(const void* g, void* l) {
  __builtin_amdgcn_global_load_lds(
      (const __attribute__((address_space(1))) unsigned int*)g,
      (__attribute__((address_space(3))) unsigned int*)l,
      16, 0, 0);
}

// ---------------- k_prep: weight conversion (gw folded) + input RMSNorm ----------------
__global__ __launch_bounds__(256) void k_prep(const float* __restrict__ wi, const float* __restrict__ wo,
                                              const float* __restrict__ gw, const float* __restrict__ x,
                                              const float* __restrict__ nw,
                                              ushort* __restrict__ oi, ushort* __restrict__ oo,
                                              ushort* __restrict__ u) {
  const int CVT_BLKS = (NPAD * DMODEL + DMODEL * DINNER) / 256;   // 6912
  int bid = blockIdx.x;
  if (bid < CVT_BLKS) {
    int idx = bid * 256 + threadIdx.x;
    const int n1 = NPAD * DMODEL;
    if (idx < n1) {
      int n = idx / DMODEL, k = idx % DMODEL;
      oi[idx] = f2bf((n < NPROJ) ? wi[(size_t)n * DMODEL + k] : 0.f);
    } else {
      int j = idx - n1;
      oo[j] = f2bf(wo[j] * gw[j & (DINNER - 1)]);
    }
    return;
  }
  int row = (bid - CVT_BLKS) * 4 + (threadIdx.x >> 6);
  int lane = threadIdx.x & 63;
  const float* xr = x + (size_t)row * DMODEL + lane * 8;
  float4 a = *(const float4*)xr;
  float4 b = *(const float4*)(xr + 4);
  float ss = a.x*a.x + a.y*a.y + a.z*a.z + a.w*a.w + b.x*b.x + b.y*b.y + b.z*b.z + b.w*b.w;
  ss += __shfl_xor(ss, 1);  ss += __shfl_xor(ss, 2);  ss += __shfl_xor(ss, 4);
  ss += __shfl_xor(ss, 8);  ss += __shfl_xor(ss, 16); ss += __shfl_xor(ss, 32);
  float sc = rsqrtf(ss * (1.f / DMODEL) + 1e-6f);
  const float* wr = nw + lane * 8;
  float4 wa = *(const float4*)wr;
  float4 wb = *(const float4*)(wr + 4);
  union { ushort s[8]; int4 v; } o;
  o.s[0] = f2bf(a.x * wa.x * sc); o.s[1] = f2bf(a.y * wa.y * sc);
  o.s[2] = f2bf(a.z * wa.z * sc); o.s[3] = f2bf(a.w * wa.w * sc);
  o.s[4] = f2bf(b.x * wb.x * sc); o.s[5] = f2bf(b.y * wb.y * sc);
  o.s[6] = f2bf(b.z * wb.z * sc); o.s[7] = f2bf(b.w * wb.w * sc);
  *(int4*)(u + (size_t)row * DMODEL + lane * 8) = o.v;
}

// ---------------- bf16 MFMA GEMM: 32x32x16, counted-vmcnt 2-phase dbuf, T2+XCD swizzle ----
// (r6-proven schedule, generalized to NT threads / NT/64 waves.)
// EPI 0: bf16 out; EPI 3: f32 out = v*rsqrt(rs[row]/D+eps) + resid.
template <int EPI, int BM, int BN, int MR, int NR, int NT>
__global__ __launch_bounds__(NT) void gemm_bt(const ushort* __restrict__ A, const ushort* __restrict__ Bm,
                                              void* __restrict__ Cout, const float* __restrict__ resid,
                                              const float* __restrict__ rs,
                                              int M, int N, int K, int gx) {
  constexpr int NWAVES = NT / 64;
  constexpr int WM = MR * 32, WN = NR * 32;
  constexpr int WAVES_N = BN / WN;              // WAVES_M * WAVES_N == NWAVES
  constexpr int CH_A = BM / 8, CH_B = BN / 8;   // 1KB chunks per tile
  constexpr int PER_A = CH_A / NWAVES, PER_B = CH_B / NWAVES;
  constexpr int SL = PER_A + PER_B;             // stage loads per thread
  __shared__ __align__(16) ushort lA[2][BM * 64];
  __shared__ __align__(16) ushort lB[2][BN * 64];
  const int nwg = gridDim.x;
  const int cpx = nwg >> 3;                     // nwg % 8 == 0 (bijective XCD swizzle)
  const int bid = blockIdx.x;
  const int swz = (bid & 7) * cpx + (bid >> 3);
  const int n0 = (swz % gx) * BN, m0 = (swz / gx) * BM;
  const int t = threadIdx.x;
  const int wave = t >> 6, lane = t & 63;
  const int wr = wave / WAVES_N, wc = wave % WAVES_N;
  const int r3 = lane >> 3;                     // row within 8-row chunk
  const int ce = (((lane & 7) ^ r3) << 3);      // inverse-swizzled element col (16B granule)
  const int nt = K >> 6;
  f32x16 acc[MR][NR] = {};
  auto stage = [&](int buf, int k0) {
#pragma unroll
    for (int i = 0; i < PER_A; ++i) {
      int chunk = wave * PER_A + i;
      int row = chunk * 8 + r3;
      gl_lds16(A + (size_t)(m0 + row) * K + k0 + ce, (char*)&lA[buf][0] + chunk * 1024);
    }
#pragma unroll
    for (int i = 0; i < PER_B; ++i) {
      int chunk = wave * PER_B + i;
      int row = chunk * 8 + r3;
      gl_lds16(Bm + (size_t)(n0 + row) * K + k0 + ce, (char*)&lB[buf][0] + chunk * 1024);
    }
  };
  stage(0, 0);
  const int rsel = lane & 31;                   // A/B fragment row for 32x32x16
  const int khi = (lane >> 5) << 3;             // k-offset 0 or 8
  const int kswz = (lane & 7) << 3;             // read-side XOR (row&7 == lane&7)
  for (int kt = 0; kt < nt; ++kt) {
    const int cur = kt & 1;
    if (kt + 1 < nt) {
      stage(cur ^ 1, (kt + 1) << 6);            // next tile's loads stay in flight across compute
      if constexpr (SL == 12) asm volatile("s_waitcnt vmcnt(12)" ::: "memory");
      else if constexpr (SL == 8) asm volatile("s_waitcnt vmcnt(8)" ::: "memory");
      else if constexpr (SL == 6) asm volatile("s_waitcnt vmcnt(6)" ::: "memory");
      else asm volatile("s_waitcnt vmcnt(0)" ::: "memory");
    } else {
      asm volatile("s_waitcnt vmcnt(0)" ::: "memory");
    }
    __builtin_amdgcn_s_barrier();               // all waves' buf[cur] landed
#pragma unroll
    for (int kk = 0; kk < 64; kk += 16) {
      const int kcol = (kk + khi) ^ kswz;
      bf16x8 af[MR], bfr[NR];
#pragma unroll
      for (int m = 0; m < MR; ++m)
        af[m] = *reinterpret_cast<const bf16x8*>(&lA[cur][(wr * WM + m * 32 + rsel) * 64 + kcol]);
#pragma unroll
      for (int n = 0; n < NR; ++n)
        bfr[n] = *reinterpret_cast<const bf16x8*>(&lB[cur][(wc * WN + n * 32 + rsel) * 64 + kcol]);
#pragma unroll
      for (int m = 0; m < MR; ++m)
#pragma unroll
        for (int n = 0; n < NR; ++n)
          acc[m][n] = __builtin_amdgcn_mfma_f32_32x32x16_bf16(af[m], bfr[n], acc[m][n], 0, 0, 0);
    }
    __builtin_amdgcn_s_barrier();               // all waves done reading buf[cur]
  }
  // C/D layout (measured m74/m101): col = lane&31, row = (r&3) + 8*(r>>2) + 4*(lane>>5)
  const int coln = lane & 31;
  const int rbase = (lane >> 5) << 2;
#pragma unroll
  for (int m = 0; m < MR; ++m) {
#pragma unroll
    for (int n = 0; n < NR; ++n) {
      int gm0 = m0 + wr * WM + m * 32 + rbase;
      int gn = n0 + wc * WN + n * 32 + coln;
#pragma unroll
      for (int r = 0; r < 16; ++r) {
        int gm = gm0 + (r & 3) + 8 * (r >> 2);
        float v = acc[m][n][r];
        if (EPI == 0) {
          ((ushort*)Cout)[(size_t)gm * N + gn] = f2bf(v);
        } else {
          float sc_ = rsqrtf(rs[gm] * (1.f / DINNER) + 1e-5f);
          ((float*)Cout)[(size_t)gm * N + gn] = v * sc_ + resid[(size_t)gm * N + gn];
        }
      }
    }
  }
}

// ---------------- k_convdt: depthwise conv+silu (2 channels/thread) -> XT/BT/convBC(swz);
// blocks [0,640): conv; blocks [640, 640+512): dt softplus + per-chunk cumsum. ----------
__global__ __launch_bounds__(256) void k_convdt(const ushort* __restrict__ zx, const float* __restrict__ cw,
                                                const float* __restrict__ cb, const float* __restrict__ dt_bias,
                                                const float* __restrict__ A_log,
                                                ushort* __restrict__ convBC, ushort* __restrict__ XT,
                                                ushort* __restrict__ BT,
                                                float* __restrict__ dtb, float* __restrict__ acum,
                                                float* __restrict__ rs) {
  const int CONV_BLKS = CONVDIM / 2 * 256 / 256;   // 640
  int bid = blockIdx.x;
  if (bid >= CONV_BLKS) {
    int flat = (bid - CONV_BLKS) * 256 + threadIdx.x;
    if (flat < ML) rs[flat] = 0.f;                   // zero row-sumsq accumulator
    int gid = (bid - CONV_BLKS) * 4 + (threadIdx.x >> 6);
    int lane = threadIdx.x & 63;
    int c = gid & 31, h = (gid >> 5) & 15, b = gid >> 9;
    int row = b * L_ + c * Q_ + lane;
    float raw = bf2f(zx[(size_t)row * NPAD + DINNER + CONVDIM + h]) + dt_bias[h];
    float dtv = raw > 20.f ? raw : log1pf(expf(raw));
    dtb[(size_t)row * NH + h] = dtv;
    float a = dtv * (-__expf(A_log[h]));
#pragma unroll
    for (int d = 1; d < 64; d <<= 1) {
      float o = __shfl_up(a, d);
      if (lane >= d) a += o;
    }
    acum[(size_t)row * NH + h] = a;
    return;
  }
  int t = bid * 256 + threadIdx.x;
  int cp = t % (CONVDIM / 2);        // channel pair 0..639
  int ch = cp * 2;
  int rb = t / (CONVDIM / 2);        // b*64 + lb
  int lb = rb & 63, b = rb >> 6;
  int l0 = lb * 32;
  float4 wv0 = *(const float4*)(cw + ch * 4);
  float4 wv1 = *(const float4*)(cw + ch * 4 + 4);
  float bias0 = cb[ch], bias1 = cb[ch + 1];
  const size_t rowb = (size_t)b * L_;
  const ushort* ip = zx + (rowb + l0) * NPAD + DINNER + ch;
  float x00 = 0.f, x01 = 0.f, x02 = 0.f;   // channel ch history
  float x10 = 0.f, x11 = 0.f, x12 = 0.f;   // channel ch+1 history
  if (l0 >= 3) {
    uint u3 = *(const uint*)(ip - 3 * NPAD);
    uint u2 = *(const uint*)(ip - 2 * NPAD);
    uint u1 = *(const uint*)(ip - 1 * NPAD);
    x00 = bf2f((ushort)u3); x10 = bf2f((ushort)(u3 >> 16));
    x01 = bf2f((ushort)u2); x11 = bf2f((ushort)(u2 >> 16));
    x02 = bf2f((ushort)u1); x12 = bf2f((ushort)(u1 >> 16));
  }
  ushort* xdst = nullptr; ushort* bdst = nullptr;
  ushort* bcb2 = nullptr; int col0 = 0;
  if (ch < DINNER) {
    int h = ch >> 6, p = ch & 63;
    xdst = XT + ((size_t)(b * NH + h) * HD + p) * L_ + l0;   // rows p and p+1
  } else if (ch < DINNER + DSTATE) {
    int n = ch - DINNER;
    bdst = BT + ((size_t)b * DSTATE + n) * L_ + l0;          // rows n and n+1
    bcb2 = convBC + (rowb + l0) * 256; col0 = n;
  } else {
    int n = ch - DINNER - DSTATE;
    bcb2 = convBC + (rowb + l0) * 256; col0 = 128 + n;
  }
  union U8 { int4 v; ushort s[8]; } buf0, buf1;
#pragma unroll
  for (int i = 0; i < 32; ++i) {
    uint uv = *(const uint*)(ip + (size_t)i * NPAD);
    float xa = bf2f((ushort)uv), xb = bf2f((ushort)(uv >> 16));
    float v0 = wv0.x * x00 + wv0.y * x01 + wv0.z * x02 + wv0.w * xa + bias0;
    float v1 = wv1.x * x10 + wv1.y * x11 + wv1.z * x12 + wv1.w * xb + bias1;
    ushort s0 = f2bf(siluf(v0)), s1 = f2bf(siluf(v1));
    x00 = x01; x01 = x02; x02 = xa;
    x10 = x11; x11 = x12; x12 = xb;
    buf0.s[i & 7] = s0; buf1.s[i & 7] = s1;
    if (bcb2) *(uint*)&bcb2[(size_t)i * 256 + (col0 ^ ((i & 7) << 3))] = (uint)s0 | ((uint)s1 << 16);
    if ((i & 7) == 7) {
      int base = i & ~7;
      if (xdst) { *(int4*)(xdst + base) = buf0.v; *(int4*)(xdst + L_ + base) = buf1.v; }
      if (bdst) { *(int4*)(bdst + base) = buf0.v; *(int4*)(bdst + L_ + base) = buf1.v; }
    }
  }
}

// ---------------- k_state: S[p][n] = sum_t (w[t]*X[t,p]) * B[t,n]; S written pre-swizzled ----
__global__ __launch_bounds__(256) void k_state(const ushort* __restrict__ XT, const ushort* __restrict__ BT,
                                               const float* __restrict__ dtb, const float* __restrict__ acum,
                                               ushort* __restrict__ Sbuf) {
  __shared__ __align__(16) ushort sXW[64 * 72];   // weighted X^T [p][t], padded stride
  __shared__ __align__(16) ushort sBT[128 * 64];  // B^T [n][t], linear (gl_lds16, swizzled src)
  __shared__ float sDt[64], sCum[64], sW[64];
  const int blk = blockIdx.x;
  const int c = blk & 31, h = (blk >> 5) & 15, b = blk >> 9;
  const int row0 = b * L_ + c * Q_;
  const int tid = threadIdx.x;
  const int wave = tid >> 6, lane = tid & 63;
  const int r3 = lane >> 3;
  const int ce = (((lane & 7) ^ r3) << 3);
  const ushort* btb = BT + (size_t)b * DSTATE * L_ + c * Q_;
#pragma unroll
  for (int i = 0; i < 4; ++i) {
    int chunk = wave * 4 + i;
    int row = chunk * 8 + r3;
    gl_lds16(btb + (size_t)row * L_ + ce, (char*)sBT + chunk * 1024);
  }
  if (tid < 64) {
    sDt[tid]  = dtb[(size_t)(row0 + tid) * NH + h];
    sCum[tid] = acum[(size_t)(row0 + tid) * NH + h];
  }
  __syncthreads();
  if (tid < 64) sW[tid] = sDt[tid] * __expf(sCum[63] - sCum[tid]);
  __syncthreads();
  const ushort* xtb = XT + (size_t)(b * NH + h) * HD * L_ + c * Q_;
#pragma unroll
  for (int j = 0; j < 2; ++j) {
    int u = tid * 2 + j;
    int p = u >> 3, t8 = (u & 7) * 8;
    union { int4 v; ushort s[8]; } xv, ov;
    xv.v = *(const int4*)(xtb + (size_t)p * L_ + t8);
    float4 wa = *(const float4*)&sW[t8];
    float4 wb2 = *(const float4*)&sW[t8 + 4];
    ov.s[0] = f2bf(bf2f(xv.s[0]) * wa.x); ov.s[1] = f2bf(bf2f(xv.s[1]) * wa.y);
    ov.s[2] = f2bf(bf2f(xv.s[2]) * wa.z); ov.s[3] = f2bf(bf2f(xv.s[3]) * wa.w);
    ov.s[4] = f2bf(bf2f(xv.s[4]) * wb2.x); ov.s[5] = f2bf(bf2f(xv.s[5]) * wb2.y);
    ov.s[6] = f2bf(bf2f(xv.s[6]) * wb2.z); ov.s[7] = f2bf(bf2f(xv.s[7]) * wb2.w);
    *(int4*)&sXW[p * 72 + t8] = ov.v;
  }
  asm volatile("s_waitcnt vmcnt(0)" ::: "memory");
  __syncthreads();
  const int rsel = lane & 31;
  const int khi = (lane >> 5) << 3;
  const int kswz = (lane & 7) << 3;
  f32x16 acc[2] = {};                         // 64p (MR=2) x this wave's 32n slice
#pragma unroll
  for (int kk = 0; kk < 64; kk += 16) {
    const int kA = kk + khi;                  // padded buffer: no swizzle
    const int kB = kA ^ kswz;                 // swizzled read (row&7 == lane&7)
    bf16x8 bfrg = *(const bf16x8*)&sBT[(wave * 32 + rsel) * 64 + kB];
#pragma unroll
    for (int m = 0; m < 2; ++m) {
      bf16x8 afrg = *(const bf16x8*)&sXW[(m * 32 + rsel) * 72 + kA];
      acc[m] = __builtin_amdgcn_mfma_f32_32x32x16_bf16(afrg, bfrg, acc[m], 0, 0, 0);
    }
  }
  ushort* Sp = Sbuf + (size_t)((b * NH + h) * NCH + c) * (HD * DSTATE);
  const int ncol = wave * 32 + (lane & 31);
  const int rbase = (lane >> 5) << 2;
#pragma unroll
  for (int m = 0; m < 2; ++m)
#pragma unroll
    for (int r = 0; r < 16; ++r) {
      int prow = m * 32 + rbase + (r & 3) + 8 * (r >> 2);
      Sp[prow * DSTATE + (ncol ^ ((prow & 7) << 3))] = f2bf(acc[m][r]);   // pre-swizzled global
    }
}

// ---------------- inter-chunk state scan (in-place: S -> h_in), depth-4 prefetch ----------
// (position-wise across chunks; operates on swizzled S consistently, swizzle key = p only)
__global__ __launch_bounds__(256) void k_scan2(ushort* __restrict__ Sbuf, const float* __restrict__ acum) {
  const int blk = blockIdx.x;           // 256 = bh*4 + ps
  const int ps = blk & 3, bh = blk >> 2;
  const int b = bh >> 4, h = bh & 15;
  const int off = ps * 2048 + threadIdx.x * 8;
  ushort* base = Sbuf + (size_t)bh * NCH * (HD * DSTATE) + off;
  float alphas[NCH];
#pragma unroll
  for (int c = 0; c < NCH; ++c)
    alphas[c] = __expf(acum[(size_t)(b * L_ + c * Q_ + 63) * NH + h]);
  union U8 { int4 v; ushort s[8]; };
  U8 pf[4];
#pragma unroll
  for (int i = 0; i < 4; ++i) pf[i].v = *(const int4*)(base + (size_t)i * (HD * DSTATE));
  float hreg[8] = {};
  U8 hv;
#pragma unroll
  for (int c = 0; c < NCH; ++c) {
    U8 cur = pf[c & 3];
    if (c + 4 < NCH) pf[c & 3].v = *(const int4*)(base + (size_t)(c + 4) * (HD * DSTATE));
#pragma unroll
    for (int i = 0; i < 8; ++i) hv.s[i] = f2bf(hreg[i]);
    *(int4*)(base + (size_t)c * (HD * DSTATE)) = hv.v;   // h_in for chunk c
#pragma unroll
    for (int i = 0; i < 8; ++i) hreg[i] = fmaf(alphas[c], hreg[i], bf2f(cur.s[i]));
  }
}

// ---------------- k_y: Y = M@X + exp(cum).*(C@h_in^T) + D.*x, gated by silu(z); row-ss ----
__global__ __launch_bounds__(256) void k_y(const ushort* __restrict__ convBC, const ushort* __restrict__ XT,
                                           const ushort* __restrict__ zx, const ushort* __restrict__ Hin,
                                           const float* __restrict__ dtb, const float* __restrict__ acum,
                                           const float* __restrict__ Dp, ushort* __restrict__ yb,
                                           float* __restrict__ rs) {
  __shared__ __align__(16) ushort sBC[64 * 256];  // B|C tile (swizzled-in-global, linear DMA)
  __shared__ __align__(16) ushort sH[64 * 128];   // h_in (swizzled-in-global, linear DMA)
  __shared__ __align__(16) ushort sM[64 * 72];    // M matrix (padded, VALU-built)
  __shared__ __align__(16) ushort sXS[64 * 64];   // X^T (linear; swizzled-src DMA)
  __shared__ float sDt[64], sCum[64];
  const int blk = blockIdx.x;
  const int c = blk & 31, h = (blk >> 5) & 15, b = blk >> 9;
  const int row0 = b * L_ + c * Q_;
  const int tid = threadIdx.x;
  const int wave = tid >> 6, lane = tid & 63;
  const int r3 = lane >> 3;
  const int ce = (((lane & 7) ^ r3) << 3);
  // DMA-stage sBC (32KB contiguous) and sH (16KB contiguous)
  const char* bcb = (const char*)(convBC + (size_t)row0 * 256);
#pragma unroll
  for (int i = 0; i < 8; ++i) {
    int chunk = wave * 8 + i;
    gl_lds16(bcb + chunk * 1024 + lane * 16, (char*)sBC + chunk * 1024);
  }
  const char* Hp = (const char*)(Hin + (size_t)((b * NH + h) * NCH + c) * (HD * DSTATE));
#pragma unroll
  for (int i = 0; i < 4; ++i) {
    int chunk = wave * 4 + i;
    gl_lds16(Hp + chunk * 1024 + lane * 16, (char*)sH + chunk * 1024);
  }
  const ushort* xtb = XT + (size_t)(b * NH + h) * HD * L_ + c * Q_;
#pragma unroll
  for (int i = 0; i < 2; ++i) {
    int chunk = wave * 2 + i;
    int row = chunk * 8 + r3;
    gl_lds16(xtb + (size_t)row * L_ + ce, (char*)sXS + chunk * 1024);
  }
  if (tid < 64) {
    sDt[tid]  = dtb[(size_t)(row0 + tid) * NH + h];
    sCum[tid] = acum[(size_t)(row0 + tid) * NH + h];
  }
  // T14 issue-early: hoist the 16 scattered z loads above the MFMA phases
  const int t0 = wave * 16;
  ushort zr_[16];
  {
    int trow0 = t0 + ((lane >> 4) << 2);
    const ushort* zp = zx + (size_t)row0 * NPAD + h * HD;
#pragma unroll
    for (int p = 0; p < 4; ++p) {
      int pc = p * 16 + (lane & 15);
#pragma unroll
      for (int r = 0; r < 4; ++r)
        zr_[p * 4 + r] = zp[(size_t)(trow0 + r) * NPAD + pc];
    }
  }
  asm volatile("s_waitcnt vmcnt(0)" ::: "memory");
  __syncthreads();
  const int rsel = lane & 15;
  const int rk = (rsel & 7) << 3;               // read-side XOR (all fragment rows ≡ rsel mod 8)
  // G = C @ B^T (64x64, K=128) and Yinter = C @ H^T (64x64, K=128)
  f32x4 g[4] = {};
  f32x4 y2[4] = {};
#pragma unroll
  for (int k0 = 0; k0 < 128; k0 += 32) {
    int ksel = k0 + ((lane >> 4) << 3);
    int kx = ksel ^ rk;
    bf16x8 af = *(const bf16x8*)&sBC[(t0 + rsel) * 256 + 128 + kx];   // C row t
#pragma unroll
    for (int s = 0; s < 4; ++s) {
      bf16x8 bf_ = *(const bf16x8*)&sBC[(s * 16 + rsel) * 256 + kx];  // B row t'
      g[s] = __builtin_amdgcn_mfma_f32_16x16x32_bf16(af, bf_, g[s], 0, 0, 0);
      bf16x8 hf = *(const bf16x8*)&sH[(s * 16 + rsel) * 128 + kx];    // H row p
      y2[s] = __builtin_amdgcn_mfma_f32_16x16x32_bf16(af, hf, y2[s], 0, 0, 0);
    }
  }
  // M: each wave writes ONLY its own 16 rows of sM, which only it reads below.
  {
    int trow = t0 + ((lane >> 4) << 2);
#pragma unroll
    for (int s = 0; s < 4; ++s) {
      int sc_ = s * 16 + (lane & 15);
      float dts = sDt[sc_], cums = sCum[sc_];
#pragma unroll
      for (int r = 0; r < 4; ++r) {
        int t2 = trow + r;
        float mv = (sc_ <= t2) ? g[s][r] * dts * __expf(sCum[t2] - cums) : 0.f;
        sM[t2 * 72 + sc_] = f2bf(mv);
      }
    }
  }
  // Yintra = M @ X (64x64, K=64); X B-frag from swizzled sXS
  f32x4 yi[4] = {};
#pragma unroll
  for (int k0 = 0; k0 < 64; k0 += 32) {
    int ksel = k0 + ((lane >> 4) << 3);
    bf16x8 af = *(const bf16x8*)&sM[(t0 + rsel) * 72 + ksel];
#pragma unroll
    for (int p = 0; p < 4; ++p) {
      bf16x8 bf_ = *(const bf16x8*)&sXS[(p * 16 + rsel) * 64 + (ksel ^ rk)];
      yi[p] = __builtin_amdgcn_mfma_f32_16x16x32_bf16(af, bf_, yi[p], 0, 0, 0);
    }
  }
  const float Dh = Dp[h];
  int trow = t0 + ((lane >> 4) << 2);
  float rsum[4] = {0.f, 0.f, 0.f, 0.f};
#pragma unroll
  for (int p = 0; p < 4; ++p) {
    int pc = p * 16 + (lane & 15);
#pragma unroll
    for (int r = 0; r < 4; ++r) {
      int t2 = trow + r;
      float xval = bf2f(sXS[pc * 64 + (t2 ^ ((pc & 7) << 3))]);
      float v = yi[p][r] + __expf(sCum[t2]) * y2[p][r] + Dh * xval;
      float zf = bf2f(zr_[p * 4 + r]);
      float gg = v * siluf(zf);
      rsum[r] += gg * gg;
      yb[(size_t)(row0 + t2) * DINNER + h * HD + pc] = f2bf(gg);
    }
  }
#pragma unroll
  for (int r = 0; r < 4; ++r) {
    float s = rsum[r];
    s += __shfl_xor(s, 1); s += __shfl_xor(s, 2); s += __shfl_xor(s, 4); s += __shfl_xor(s, 8);
    if ((lane & 15) == 0) atomicAdd(&rs[row0 + trow + r], s);
  }
}

extern "C" void kernel_launch(void* const* d_in, const int* in_sizes, int n_in,
                              void* d_out, int out_size, void* d_ws, size_t ws_size,
                              hipStream_t stream) {
  const float* x         = (const float*)d_in[0];
  const float* norm_w    = (const float*)d_in[1];
  const float* in_proj_w = (const float*)d_in[2];
  const float* conv_w    = (const float*)d_in[3];
  const float* conv_b    = (const float*)d_in[4];
  const float* dt_bias   = (const float*)d_in[5];
  const float* A_log     = (const float*)d_in[6];
  const float* D_param   = (const float*)d_in[7];
  const float* gnw       = (const float*)d_in[8];
  const float* out_proj_w= (const float*)d_in[9];

  char* ws = (char*)d_ws;
  ushort* u      = (ushort*)(ws + 0);            //  8,388,608  u bf16 [8192][512] (dead after GEMM1)
  ushort* convBC = (ushort*)(ws + 0);            //  4,194,304  B,C swizzled [8192][256] (aliases u)
  ushort* BT     = (ushort*)(ws + 4194304);      //  2,097,152  B^T [4][128][2048]   (aliases u)
  float*  rs     = (float*)(ws + 6291456);       //     32,768  row sumsq            (aliases u)
  ushort* Wb     = (ushort*)(ws + 8388608);      //  2,490,368  in_proj bf16 [2432][512]
  ushort* Woutb  = (ushort*)(ws + 10878976);     //  1,048,576  out_proj*gw bf16 [512][1024]
  float*  dtb    = (float*)(ws + 11927552);      //    524,288  dt [8192][16]
  float*  acum   = (float*)(ws + 12451840);      //    524,288  chunk-local cumsum [8192][16]
  ushort* zx     = (ushort*)(ws + 12976128);     // 39,845,888  zxbcdt bf16 [8192][2432]
  ushort* XT     = (ushort*)(ws + 52822016);     // 16,777,216  X^T [4][16][64][2048]
  ushort* yb     = (ushort*)(ws + 69599232);     // 16,777,216  yg bf16 [8192][1024]
  ushort* Sbuf   = (ushort*)(ws + 86376448);     // 33,554,432  chunk states (swizzled) [2048][64][128]

  const int CVT_BLKS = (NPAD * DMODEL + DMODEL * DINNER) / 256;   // 6912
  k_prep<<<CVT_BLKS + ML / 4, 256, 0, stream>>>(in_proj_w, out_proj_w, gnw, x, norm_w, Wb, Woutb, u);
  // GEMM1: 128x128 tiles, 256 thr (4 waves of 64x64), grid 19*64=1216 (%8==0)
  gemm_bt<0, 128, 128, 2, 2, 256><<<(NPAD / 128) * (ML / 128), 256, 0, stream>>>(u, Wb, (void*)zx, nullptr, nullptr, ML, NPAD, DMODEL, NPAD / 128);
  k_convdt<<<640 + 512, 256, 0, stream>>>(zx, conv_w, conv_b, dt_bias, A_log, convBC, XT, BT, dtb, acum, rs);
  k_state<<<2048, 256, 0, stream>>>(XT, BT, dtb, acum, Sbuf);
  k_scan2<<<256, 256, 0, stream>>>(Sbuf, acum);
  k_y<<<2048, 256, 0, stream>>>(convBC, XT, zx, Sbuf, dtb, acum, D_param, yb, rs);
  // GEMM2: r11-proven config — 128x64 tiles, 256 thr, grid 8*64=512 (%8==0)
  gemm_bt<3, 128, 64, 2, 1, 256><<<(DMODEL / 64) * (ML / 128), 256, 0, stream>>>(yb, Woutb, d_out, x, rs, ML, DMODEL, DINNER, DMODEL / 64);
}

// Round 15
// 138.138 us; speedup vs baseline: 1.0273x; 1.0273x over previous
//
#include <hip/hip_runtime.h>
#include <cstdint>
#include <cstddef>

#define B_ 4
#define L_ 2048
#define DMODEL 512
#define DINNER 1024
#define DSTATE 128
#define NH 16
#define HD 64
#define CONVDIM 1280          // DINNER + 2*DSTATE
#define NPROJ 2320            // 2*DINNER + 2*DSTATE + NH
#define NPAD 2432             // 19 * 128
#define ML (B_*L_)            // 8192 rows
#define Q_ 64                 // chunk length
#define NCH 32                // chunks per sequence

typedef __bf16 bf16x8 __attribute__((ext_vector_type(8)));
typedef float f32x4 __attribute__((ext_vector_type(4)));
typedef float f32x16 __attribute__((ext_vector_type(16)));

__device__ __forceinline__ float bf2f(ushort u) {
  union { unsigned int i; float f; } v; v.i = ((unsigned int)u) << 16; return v.f;
}
__device__ __forceinline__ ushort f2bf(float f) {
  union { float f; unsigned int i; } v; v.f = f;
  unsigned int u = v.i;
  unsigned int r = (u + 0x7fffu + ((u >> 16) & 1u)) >> 16;
  return (ushort)r;
}
__device__ __forceinline__ float siluf(float x) { return x / (1.f + __expf(-x)); }

// async global->LDS, 16B per lane; LDS dest is wave-uniform base + lane*16
__device__ __forceinline__ void gl_lds16(const void* g, void* l) {
  __builtin_amdgcn_global_load_lds(
      (const __attribute__((address_space(1))) unsigned int*)g,
      (__attribute__((address_space(3))) unsigned int*)l,
      16, 0, 0);
}

// ---------------- k_prep: weight conversion (gw folded) + input RMSNorm ----------------
__global__ __launch_bounds__(256) void k_prep(const float* __restrict__ wi, const float* __restrict__ wo,
                                              const float* __restrict__ gw, const float* __restrict__ x,
                                              const float* __restrict__ nw,
                                              ushort* __restrict__ oi, ushort* __restrict__ oo,
                                              ushort* __restrict__ u) {
  const int CVT_BLKS = (NPAD * DMODEL + DMODEL * DINNER) / 256;   // 6912
  int bid = blockIdx.x;
  if (bid < CVT_BLKS) {
    int idx = bid * 256 + threadIdx.x;
    const int n1 = NPAD * DMODEL;
    if (idx < n1) {
      int n = idx / DMODEL, k = idx % DMODEL;
      oi[idx] = f2bf((n < NPROJ) ? wi[(size_t)n * DMODEL + k] : 0.f);
    } else {
      int j = idx - n1;
      oo[j] = f2bf(wo[j] * gw[j & (DINNER - 1)]);
    }
    return;
  }
  int row = (bid - CVT_BLKS) * 4 + (threadIdx.x >> 6);
  int lane = threadIdx.x & 63;
  const float* xr = x + (size_t)row * DMODEL + lane * 8;
  float4 a = *(const float4*)xr;
  float4 b = *(const float4*)(xr + 4);
  float ss = a.x*a.x + a.y*a.y + a.z*a.z + a.w*a.w + b.x*b.x + b.y*b.y + b.z*b.z + b.w*b.w;
  ss += __shfl_xor(ss, 1);  ss += __shfl_xor(ss, 2);  ss += __shfl_xor(ss, 4);
  ss += __shfl_xor(ss, 8);  ss += __shfl_xor(ss, 16); ss += __shfl_xor(ss, 32);
  float sc = rsqrtf(ss * (1.f / DMODEL) + 1e-6f);
  const float* wr = nw + lane * 8;
  float4 wa = *(const float4*)wr;
  float4 wb = *(const float4*)(wr + 4);
  union { ushort s[8]; int4 v; } o;
  o.s[0] = f2bf(a.x * wa.x * sc); o.s[1] = f2bf(a.y * wa.y * sc);
  o.s[2] = f2bf(a.z * wa.z * sc); o.s[3] = f2bf(a.w * wa.w * sc);
  o.s[4] = f2bf(b.x * wb.x * sc); o.s[5] = f2bf(b.y * wb.y * sc);
  o.s[6] = f2bf(b.z * wb.z * sc); o.s[7] = f2bf(b.w * wb.w * sc);
  *(int4*)(u + (size_t)row * DMODEL + lane * 8) = o.v;
}

// ---------------- bf16 MFMA GEMM: 32x32x16, counted-vmcnt 2-phase dbuf, T2+XCD swizzle ----
// (r6-proven schedule, generalized to NT threads / NT/64 waves.)
// EPI 0: bf16 out; EPI 3: f32 out = v*rsqrt(rs[row]/D+eps) + resid.
template <int EPI, int BM, int BN, int MR, int NR, int NT>
__global__ __launch_bounds__(NT) void gemm_bt(const ushort* __restrict__ A, const ushort* __restrict__ Bm,
                                              void* __restrict__ Cout, const float* __restrict__ resid,
                                              const float* __restrict__ rs,
                                              int M, int N, int K, int gx) {
  constexpr int NWAVES = NT / 64;
  constexpr int WM = MR * 32, WN = NR * 32;
  constexpr int WAVES_N = BN / WN;              // WAVES_M * WAVES_N == NWAVES
  constexpr int CH_A = BM / 8, CH_B = BN / 8;   // 1KB chunks per tile
  constexpr int PER_A = CH_A / NWAVES, PER_B = CH_B / NWAVES;
  constexpr int SL = PER_A + PER_B;             // stage loads per thread
  __shared__ __align__(16) ushort lA[2][BM * 64];
  __shared__ __align__(16) ushort lB[2][BN * 64];
  const int nwg = gridDim.x;
  const int cpx = nwg >> 3;                     // nwg % 8 == 0 (bijective XCD swizzle)
  const int bid = blockIdx.x;
  const int swz = (bid & 7) * cpx + (bid >> 3);
  const int n0 = (swz % gx) * BN, m0 = (swz / gx) * BM;
  const int t = threadIdx.x;
  const int wave = t >> 6, lane = t & 63;
  const int wr = wave / WAVES_N, wc = wave % WAVES_N;
  const int r3 = lane >> 3;                     // row within 8-row chunk
  const int ce = (((lane & 7) ^ r3) << 3);      // inverse-swizzled element col (16B granule)
  const int nt = K >> 6;
  f32x16 acc[MR][NR] = {};
  auto stage = [&](int buf, int k0) {
#pragma unroll
    for (int i = 0; i < PER_A; ++i) {
      int chunk = wave * PER_A + i;
      int row = chunk * 8 + r3;
      gl_lds16(A + (size_t)(m0 + row) * K + k0 + ce, (char*)&lA[buf][0] + chunk * 1024);
    }
#pragma unroll
    for (int i = 0; i < PER_B; ++i) {
      int chunk = wave * PER_B + i;
      int row = chunk * 8 + r3;
      gl_lds16(Bm + (size_t)(n0 + row) * K + k0 + ce, (char*)&lB[buf][0] + chunk * 1024);
    }
  };
  stage(0, 0);
  const int rsel = lane & 31;                   // A/B fragment row for 32x32x16
  const int khi = (lane >> 5) << 3;             // k-offset 0 or 8
  const int kswz = (lane & 7) << 3;             // read-side XOR (row&7 == lane&7)
  for (int kt = 0; kt < nt; ++kt) {
    const int cur = kt & 1;
    if (kt + 1 < nt) {
      stage(cur ^ 1, (kt + 1) << 6);            // next tile's loads stay in flight across compute
      if constexpr (SL == 12) asm volatile("s_waitcnt vmcnt(12)" ::: "memory");
      else if constexpr (SL == 8) asm volatile("s_waitcnt vmcnt(8)" ::: "memory");
      else if constexpr (SL == 6) asm volatile("s_waitcnt vmcnt(6)" ::: "memory");
      else asm volatile("s_waitcnt vmcnt(0)" ::: "memory");
    } else {
      asm volatile("s_waitcnt vmcnt(0)" ::: "memory");
    }
    __builtin_amdgcn_s_barrier();               // all waves' buf[cur] landed
#pragma unroll
    for (int kk = 0; kk < 64; kk += 16) {
      const int kcol = (kk + khi) ^ kswz;
      bf16x8 af[MR], bfr[NR];
#pragma unroll
      for (int m = 0; m < MR; ++m)
        af[m] = *reinterpret_cast<const bf16x8*>(&lA[cur][(wr * WM + m * 32 + rsel) * 64 + kcol]);
#pragma unroll
      for (int n = 0; n < NR; ++n)
        bfr[n] = *reinterpret_cast<const bf16x8*>(&lB[cur][(wc * WN + n * 32 + rsel) * 64 + kcol]);
#pragma unroll
      for (int m = 0; m < MR; ++m)
#pragma unroll
        for (int n = 0; n < NR; ++n)
          acc[m][n] = __builtin_amdgcn_mfma_f32_32x32x16_bf16(af[m], bfr[n], acc[m][n], 0, 0, 0);
    }
    __builtin_amdgcn_s_barrier();               // all waves done reading buf[cur]
  }
  // C/D layout (measured m74/m101): col = lane&31, row = (r&3) + 8*(r>>2) + 4*(lane>>5)
  const int coln = lane & 31;
  const int rbase = (lane >> 5) << 2;
#pragma unroll
  for (int m = 0; m < MR; ++m) {
#pragma unroll
    for (int n = 0; n < NR; ++n) {
      int gm0 = m0 + wr * WM + m * 32 + rbase;
      int gn = n0 + wc * WN + n * 32 + coln;
#pragma unroll
      for (int r = 0; r < 16; ++r) {
        int gm = gm0 + (r & 3) + 8 * (r >> 2);
        float v = acc[m][n][r];
        if (EPI == 0) {
          ((ushort*)Cout)[(size_t)gm * N + gn] = f2bf(v);
        } else {
          float sc_ = rsqrtf(rs[gm] * (1.f / DINNER) + 1e-5f);
          ((float*)Cout)[(size_t)gm * N + gn] = v * sc_ + resid[(size_t)gm * N + gn];
        }
      }
    }
  }
}

// ---------------- k_convdt: depthwise conv+silu -> XT/BT/convBC(swizzled), plus dt/cumsum ----
// blocks [0,CONVDIM): conv; blocks [CONVDIM, CONVDIM+512): dt softplus + per-chunk cumsum.
__global__ __launch_bounds__(256) void k_convdt(const ushort* __restrict__ zx, const float* __restrict__ cw,
                                                const float* __restrict__ cb, const float* __restrict__ dt_bias,
                                                const float* __restrict__ A_log,
                                                ushort* __restrict__ convBC, ushort* __restrict__ XT,
                                                ushort* __restrict__ BT,
                                                float* __restrict__ dtb, float* __restrict__ acum,
                                                float* __restrict__ rs) {
  int bid = blockIdx.x;
  if (bid >= CONVDIM) {
    int flat = (bid - CONVDIM) * 256 + threadIdx.x;
    if (flat < ML) rs[flat] = 0.f;                   // zero row-sumsq accumulator
    int gid = (bid - CONVDIM) * 4 + (threadIdx.x >> 6);
    int lane = threadIdx.x & 63;
    int c = gid & 31, h = (gid >> 5) & 15, b = gid >> 9;
    int row = b * L_ + c * Q_ + lane;
    float raw = bf2f(zx[(size_t)row * NPAD + DINNER + CONVDIM + h]) + dt_bias[h];
    float dtv = raw > 20.f ? raw : log1pf(expf(raw));
    dtb[(size_t)row * NH + h] = dtv;
    float a = dtv * (-__expf(A_log[h]));
#pragma unroll
    for (int d = 1; d < 64; d <<= 1) {
      float o = __shfl_up(a, d);
      if (lane >= d) a += o;
    }
    acum[(size_t)row * NH + h] = a;
    return;
  }
  int t = bid * 256 + threadIdx.x;
  int ch = t % CONVDIM;
  int rb = t / CONVDIM;              // b*64 + lb
  int lb = rb & 63, b = rb >> 6;
  int l0 = lb * 32;
  float4 wv = *(const float4*)(cw + ch * 4);
  float bias = cb[ch];
  const size_t rowb = (size_t)b * L_;
  const ushort* ip = zx + (rowb + l0) * NPAD + DINNER + ch;
  float x0 = 0.f, x1 = 0.f, x2 = 0.f;
  if (l0 >= 3) {
    x0 = bf2f(ip[-3 * NPAD]); x1 = bf2f(ip[-2 * NPAD]); x2 = bf2f(ip[-1 * NPAD]);
  }
  ushort* xdst = nullptr; ushort* bdst = nullptr;
  ushort* bcb2 = nullptr; int col0 = 0;
  if (ch < DINNER) {
    int h = ch >> 6, p = ch & 63;
    xdst = XT + ((size_t)(b * NH + h) * HD + p) * L_ + l0;
  } else if (ch < DINNER + DSTATE) {
    int n = ch - DINNER;
    bdst = BT + ((size_t)b * DSTATE + n) * L_ + l0;
    bcb2 = convBC + (rowb + l0) * 256; col0 = n;
  } else {
    int n = ch - DINNER - DSTATE;
    bcb2 = convBC + (rowb + l0) * 256; col0 = 128 + n;
  }
  union U8 { int4 v; ushort s[8]; } buf;
#pragma unroll
  for (int i = 0; i < 32; ++i) {
    float x3 = bf2f(ip[(size_t)i * NPAD]);
    float v = wv.x * x0 + wv.y * x1 + wv.z * x2 + wv.w * x3 + bias;
    ushort sv = f2bf(siluf(v));
    x0 = x1; x1 = x2; x2 = x3;
    buf.s[i & 7] = sv;
    if (bcb2) bcb2[(size_t)i * 256 + (col0 ^ ((i & 7) << 3))] = sv;   // pre-swizzled global
    if ((i & 7) == 7) {
      if (xdst) *(int4*)(xdst + (i & ~7)) = buf.v;
      if (bdst) *(int4*)(bdst + (i & ~7)) = buf.v;
    }
  }
}

// ---------------- k_state: S[p][n] = sum_t (w[t]*X[t,p]) * B[t,n]; S written pre-swizzled ----
__global__ __launch_bounds__(256) void k_state(const ushort* __restrict__ XT, const ushort* __restrict__ BT,
                                               const float* __restrict__ dtb, const float* __restrict__ acum,
                                               ushort* __restrict__ Sbuf) {
  __shared__ __align__(16) ushort sXW[64 * 72];   // weighted X^T [p][t], padded stride
  __shared__ __align__(16) ushort sBT[128 * 64];  // B^T [n][t], linear (gl_lds16, swizzled src)
  __shared__ float sDt[64], sCum[64], sW[64];
  const int blk = blockIdx.x;
  const int c = blk & 31, h = (blk >> 5) & 15, b = blk >> 9;
  const int row0 = b * L_ + c * Q_;
  const int tid = threadIdx.x;
  const int wave = tid >> 6, lane = tid & 63;
  const int r3 = lane >> 3;
  const int ce = (((lane & 7) ^ r3) << 3);
  const ushort* btb = BT + (size_t)b * DSTATE * L_ + c * Q_;
#pragma unroll
  for (int i = 0; i < 4; ++i) {
    int chunk = wave * 4 + i;
    int row = chunk * 8 + r3;
    gl_lds16(btb + (size_t)row * L_ + ce, (char*)sBT + chunk * 1024);
  }
  if (tid < 64) {
    sDt[tid]  = dtb[(size_t)(row0 + tid) * NH + h];
    sCum[tid] = acum[(size_t)(row0 + tid) * NH + h];
  }
  __syncthreads();
  if (tid < 64) sW[tid] = sDt[tid] * __expf(sCum[63] - sCum[tid]);
  __syncthreads();
  const ushort* xtb = XT + (size_t)(b * NH + h) * HD * L_ + c * Q_;
#pragma unroll
  for (int j = 0; j < 2; ++j) {
    int u = tid * 2 + j;
    int p = u >> 3, t8 = (u & 7) * 8;
    union { int4 v; ushort s[8]; } xv, ov;
    xv.v = *(const int4*)(xtb + (size_t)p * L_ + t8);
    float4 wa = *(const float4*)&sW[t8];
    float4 wb2 = *(const float4*)&sW[t8 + 4];
    ov.s[0] = f2bf(bf2f(xv.s[0]) * wa.x); ov.s[1] = f2bf(bf2f(xv.s[1]) * wa.y);
    ov.s[2] = f2bf(bf2f(xv.s[2]) * wa.z); ov.s[3] = f2bf(bf2f(xv.s[3]) * wa.w);
    ov.s[4] = f2bf(bf2f(xv.s[4]) * wb2.x); ov.s[5] = f2bf(bf2f(xv.s[5]) * wb2.y);
    ov.s[6] = f2bf(bf2f(xv.s[6]) * wb2.z); ov.s[7] = f2bf(bf2f(xv.s[7]) * wb2.w);
    *(int4*)&sXW[p * 72 + t8] = ov.v;
  }
  asm volatile("s_waitcnt vmcnt(0)" ::: "memory");
  __syncthreads();
  const int rsel = lane & 31;
  const int khi = (lane >> 5) << 3;
  const int kswz = (lane & 7) << 3;
  f32x16 acc[2] = {};                         // 64p (MR=2) x this wave's 32n slice
#pragma unroll
  for (int kk = 0; kk < 64; kk += 16) {
    const int kA = kk + khi;                  // padded buffer: no swizzle
    const int kB = kA ^ kswz;                 // swizzled read (row&7 == lane&7)
    bf16x8 bfrg = *(const bf16x8*)&sBT[(wave * 32 + rsel) * 64 + kB];
#pragma unroll
    for (int m = 0; m < 2; ++m) {
      bf16x8 afrg = *(const bf16x8*)&sXW[(m * 32 + rsel) * 72 + kA];
      acc[m] = __builtin_amdgcn_mfma_f32_32x32x16_bf16(afrg, bfrg, acc[m], 0, 0, 0);
    }
  }
  ushort* Sp = Sbuf + (size_t)((b * NH + h) * NCH + c) * (HD * DSTATE);
  const int ncol = wave * 32 + (lane & 31);
  const int rbase = (lane >> 5) << 2;
#pragma unroll
  for (int m = 0; m < 2; ++m)
#pragma unroll
    for (int r = 0; r < 16; ++r) {
      int prow = m * 32 + rbase + (r & 3) + 8 * (r >> 2);
      Sp[prow * DSTATE + (ncol ^ ((prow & 7) << 3))] = f2bf(acc[m][r]);   // pre-swizzled global
    }
}

// ---------------- inter-chunk state scan (in-place: S -> h_in), depth-4 prefetch ----------
// (position-wise across chunks; operates on swizzled S consistently, swizzle key = p only)
__global__ __launch_bounds__(256) void k_scan2(ushort* __restrict__ Sbuf, const float* __restrict__ acum) {
  const int blk = blockIdx.x;           // 256 = bh*4 + ps
  const int ps = blk & 3, bh = blk >> 2;
  const int b = bh >> 4, h = bh & 15;
  const int off = ps * 2048 + threadIdx.x * 8;
  ushort* base = Sbuf + (size_t)bh * NCH * (HD * DSTATE) + off;
  float alphas[NCH];
#pragma unroll
  for (int c = 0; c < NCH; ++c)
    alphas[c] = __expf(acum[(size_t)(b * L_ + c * Q_ + 63) * NH + h]);
  union U8 { int4 v; ushort s[8]; };
  U8 pf[4];
#pragma unroll
  for (int i = 0; i < 4; ++i) pf[i].v = *(const int4*)(base + (size_t)i * (HD * DSTATE));
  float hreg[8] = {};
  U8 hv;
#pragma unroll
  for (int c = 0; c < NCH; ++c) {
    U8 cur = pf[c & 3];
    if (c + 4 < NCH) pf[c & 3].v = *(const int4*)(base + (size_t)(c + 4) * (HD * DSTATE));
#pragma unroll
    for (int i = 0; i < 8; ++i) hv.s[i] = f2bf(hreg[i]);
    *(int4*)(base + (size_t)c * (HD * DSTATE)) = hv.v;   // h_in for chunk c
#pragma unroll
    for (int i = 0; i < 8; ++i) hreg[i] = fmaf(alphas[c], hreg[i], bf2f(cur.s[i]));
  }
}

// ---------------- k_y: Y = M@X + exp(cum).*(C@h_in^T) + D.*x, gated by silu(z); row-ss ----
__global__ __launch_bounds__(256) void k_y(const ushort* __restrict__ convBC, const ushort* __restrict__ XT,
                                           const ushort* __restrict__ zx, const ushort* __restrict__ Hin,
                                           const float* __restrict__ dtb, const float* __restrict__ acum,
                                           const float* __restrict__ Dp, ushort* __restrict__ yb,
                                           float* __restrict__ rs) {
  __shared__ __align__(16) ushort sBC[64 * 256];  // B|C tile (swizzled-in-global, linear DMA)
  __shared__ __align__(16) ushort sH[64 * 128];   // h_in (swizzled-in-global, linear DMA)
  __shared__ __align__(16) ushort sM[64 * 72];    // M matrix (padded, VALU-built)
  __shared__ __align__(16) ushort sXS[64 * 64];   // X^T (linear; swizzled-src DMA)
  __shared__ float sDt[64], sCum[64];
  const int blk = blockIdx.x;
  const int c = blk & 31, h = (blk >> 5) & 15, b = blk >> 9;
  const int row0 = b * L_ + c * Q_;
  const int tid = threadIdx.x;
  const int wave = tid >> 6, lane = tid & 63;
  const int r3 = lane >> 3;
  const int ce = (((lane & 7) ^ r3) << 3);
  // DMA-stage sBC (32KB contiguous) and sH (16KB contiguous)
  const char* bcb = (const char*)(convBC + (size_t)row0 * 256);
#pragma unroll
  for (int i = 0; i < 8; ++i) {
    int chunk = wave * 8 + i;
    gl_lds16(bcb + chunk * 1024 + lane * 16, (char*)sBC + chunk * 1024);
  }
  const char* Hp = (const char*)(Hin + (size_t)((b * NH + h) * NCH + c) * (HD * DSTATE));
#pragma unroll
  for (int i = 0; i < 4; ++i) {
    int chunk = wave * 4 + i;
    gl_lds16(Hp + chunk * 1024 + lane * 16, (char*)sH + chunk * 1024);
  }
  const ushort* xtb = XT + (size_t)(b * NH + h) * HD * L_ + c * Q_;
#pragma unroll
  for (int i = 0; i < 2; ++i) {
    int chunk = wave * 2 + i;
    int row = chunk * 8 + r3;
    gl_lds16(xtb + (size_t)row * L_ + ce, (char*)sXS + chunk * 1024);
  }
  if (tid < 64) {
    sDt[tid]  = dtb[(size_t)(row0 + tid) * NH + h];
    sCum[tid] = acum[(size_t)(row0 + tid) * NH + h];
  }
  asm volatile("s_waitcnt vmcnt(0)" ::: "memory");
  __syncthreads();
  const int rsel = lane & 15;
  const int t0 = wave * 16;
  const int rk = (rsel & 7) << 3;               // read-side XOR (all fragment rows ≡ rsel mod 8)
  // G = C @ B^T (64x64, K=128) and Yinter = C @ H^T (64x64, K=128)
  f32x4 g[4] = {};
  f32x4 y2[4] = {};
#pragma unroll
  for (int k0 = 0; k0 < 128; k0 += 32) {
    int ksel = k0 + ((lane >> 4) << 3);
    int kx = ksel ^ rk;
    bf16x8 af = *(const bf16x8*)&sBC[(t0 + rsel) * 256 + 128 + kx];   // C row t
#pragma unroll
    for (int s = 0; s < 4; ++s) {
      bf16x8 bf_ = *(const bf16x8*)&sBC[(s * 16 + rsel) * 256 + kx];  // B row t'
      g[s] = __builtin_amdgcn_mfma_f32_16x16x32_bf16(af, bf_, g[s], 0, 0, 0);
      bf16x8 hf = *(const bf16x8*)&sH[(s * 16 + rsel) * 128 + kx];    // H row p
      y2[s] = __builtin_amdgcn_mfma_f32_16x16x32_bf16(af, hf, y2[s], 0, 0, 0);
    }
  }
  // M: each wave writes ONLY its own 16 rows of sM, which only it reads below.
  {
    int trow = t0 + ((lane >> 4) << 2);
#pragma unroll
    for (int s = 0; s < 4; ++s) {
      int sc_ = s * 16 + (lane & 15);
      float dts = sDt[sc_], cums = sCum[sc_];
#pragma unroll
      for (int r = 0; r < 4; ++r) {
        int t2 = trow + r;
        float mv = (sc_ <= t2) ? g[s][r] * dts * __expf(sCum[t2] - cums) : 0.f;
        sM[t2 * 72 + sc_] = f2bf(mv);
      }
    }
  }
  // Yintra = M @ X (64x64, K=64); X B-frag from swizzled sXS
  f32x4 yi[4] = {};
#pragma unroll
  for (int k0 = 0; k0 < 64; k0 += 32) {
    int ksel = k0 + ((lane >> 4) << 3);
    bf16x8 af = *(const bf16x8*)&sM[(t0 + rsel) * 72 + ksel];
#pragma unroll
    for (int p = 0; p < 4; ++p) {
      bf16x8 bf_ = *(const bf16x8*)&sXS[(p * 16 + rsel) * 64 + (ksel ^ rk)];
      yi[p] = __builtin_amdgcn_mfma_f32_16x16x32_bf16(af, bf_, yi[p], 0, 0, 0);
    }
  }
  const float Dh = Dp[h];
  int trow = t0 + ((lane >> 4) << 2);
  float rsum[4] = {0.f, 0.f, 0.f, 0.f};
#pragma unroll
  for (int p = 0; p < 4; ++p) {
    int pc = p * 16 + (lane & 15);
#pragma unroll
    for (int r = 0; r < 4; ++r) {
      int t2 = trow + r;
      float xval = bf2f(sXS[pc * 64 + (t2 ^ ((pc & 7) << 3))]);
      float v = yi[p][r] + __expf(sCum[t2]) * y2[p][r] + Dh * xval;
      float zf = bf2f(zx[(size_t)(row0 + t2) * NPAD + h * HD + pc]);
      float gg = v * siluf(zf);
      rsum[r] += gg * gg;
      yb[(size_t)(row0 + t2) * DINNER + h * HD + pc] = f2bf(gg);
    }
  }
#pragma unroll
  for (int r = 0; r < 4; ++r) {
    float s = rsum[r];
    s += __shfl_xor(s, 1); s += __shfl_xor(s, 2); s += __shfl_xor(s, 4); s += __shfl_xor(s, 8);
    if ((lane & 15) == 0) atomicAdd(&rs[row0 + trow + r], s);
  }
}

extern "C" void kernel_launch(void* const* d_in, const int* in_sizes, int n_in,
                              void* d_out, int out_size, void* d_ws, size_t ws_size,
                              hipStream_t stream) {
  const float* x         = (const float*)d_in[0];
  const float* norm_w    = (const float*)d_in[1];
  const float* in_proj_w = (const float*)d_in[2];
  const float* conv_w    = (const float*)d_in[3];
  const float* conv_b    = (const float*)d_in[4];
  const float* dt_bias   = (const float*)d_in[5];
  const float* A_log     = (const float*)d_in[6];
  const float* D_param   = (const float*)d_in[7];
  const float* gnw       = (const float*)d_in[8];
  const float* out_proj_w= (const float*)d_in[9];

  char* ws = (char*)d_ws;
  ushort* u      = (ushort*)(ws + 0);            //  8,388,608  u bf16 [8192][512] (dead after GEMM1)
  ushort* convBC = (ushort*)(ws + 0);            //  4,194,304  B,C swizzled [8192][256] (aliases u)
  ushort* BT     = (ushort*)(ws + 4194304);      //  2,097,152  B^T [4][128][2048]   (aliases u)
  float*  rs     = (float*)(ws + 6291456);       //     32,768  row sumsq            (aliases u)
  ushort* Wb     = (ushort*)(ws + 8388608);      //  2,490,368  in_proj bf16 [2432][512]
  ushort* Woutb  = (ushort*)(ws + 10878976);     //  1,048,576  out_proj*gw bf16 [512][1024]
  float*  dtb    = (float*)(ws + 11927552);      //    524,288  dt [8192][16]
  float*  acum   = (float*)(ws + 12451840);      //    524,288  chunk-local cumsum [8192][16]
  ushort* zx     = (ushort*)(ws + 12976128);     // 39,845,888  zxbcdt bf16 [8192][2432]
  ushort* XT     = (ushort*)(ws + 52822016);     // 16,777,216  X^T [4][16][64][2048]
  ushort* yb     = (ushort*)(ws + 69599232);     // 16,777,216  yg bf16 [8192][1024]
  ushort* Sbuf   = (ushort*)(ws + 86376448);     // 33,554,432  chunk states (swizzled) [2048][64][128]

  const int CVT_BLKS = (NPAD * DMODEL + DMODEL * DINNER) / 256;   // 6912
  k_prep<<<CVT_BLKS + ML / 4, 256, 0, stream>>>(in_proj_w, out_proj_w, gnw, x, norm_w, Wb, Woutb, u);
  // GEMM1: 128x128 tiles, 256 thr (4 waves of 64x64), grid 19*64=1216 (%8==0)
  gemm_bt<0, 128, 128, 2, 2, 256><<<(NPAD / 128) * (ML / 128), 256, 0, stream>>>(u, Wb, (void*)zx, nullptr, nullptr, ML, NPAD, DMODEL, NPAD / 128);
  k_convdt<<<CONVDIM + 512, 256, 0, stream>>>(zx, conv_w, conv_b, dt_bias, A_log, convBC, XT, BT, dtb, acum, rs);
  k_state<<<2048, 256, 0, stream>>>(XT, BT, dtb, acum, Sbuf);
  k_scan2<<<256, 256, 0, stream>>>(Sbuf, acum);
  k_y<<<2048, 256, 0, stream>>>(convBC, XT, zx, Sbuf, dtb, acum, D_param, yb, rs);
  // GEMM2: r11-proven config — 128x64 tiles, 256 thr, grid 8*64=512 (%8==0)
  gemm_bt<3, 128, 64, 2, 1, 256><<<(DMODEL / 64) * (ML / 128), 256, 0, stream>>>(yb, Woutb, d_out, x, rs, ML, DMODEL, DINNER, DMODEL / 64);
}